// Round 1
// baseline (432.044 us; speedup 1.0000x reference)
//
#include <hip/hip_runtime.h>

// LongformerSelfAttention (B=32,S=512,H=1024,NH=16,HD=64)
// Pipeline:
//  k_cast : hidden fp32 -> bf16
//  k_wt   : Wq/Wk/Wv (1024x1024) and Wp (1536x512) -> transposed bf16 (K-contiguous for MFMA B operand)
//  k_qkv  : Q/K/V = hs @ W + b, bf16 MFMA 128x128x32 tiles, outputs flat bf16
//  k_tr   : per-(b,n) 512x64 -> 64x512 transpose (d-major QT/KT/VT)
//  k_gv   : per-(b,n) gv GEMM (WpT @ qkv^T) + sigmoid(q.k/8) blend + gelu + output permute

typedef unsigned short ushort_t;
typedef __attribute__((ext_vector_type(8))) short short8;
typedef __attribute__((ext_vector_type(8))) unsigned short ushort8;
typedef __attribute__((ext_vector_type(4))) float f32x4;

#define ASYNC16(gp, lp) __builtin_amdgcn_global_load_lds( \
    (const __attribute__((address_space(1))) void*)(gp),  \
    (__attribute__((address_space(3))) void*)(lp), 16, 0, 0)

__device__ __forceinline__ ushort_t f2b(float f) {
  union { float f; unsigned int u; } v; v.f = f;
  unsigned int r = v.u + 0x7FFFu + ((v.u >> 16) & 1u);
  return (ushort_t)(r >> 16);
}
__device__ __forceinline__ float b2f(ushort_t b) {
  union { unsigned int u; float f; } v; v.u = ((unsigned int)b) << 16;
  return v.f;
}

// ---- workspace layout (bytes) ----
#define OFF_HSB 0ull                          // bf16[16384*1024] ; reused as QT after k_qkv
#define OFF_WQT (33554432ull)                 // bf16[1024*1024]  (WqT: [n][k])
#define OFF_WKT (OFF_WQT + 2097152ull)
#define OFF_WVT (OFF_WKT + 2097152ull)
#define OFF_WPT (OFF_WVT + 2097152ull)        // bf16[512*1536]   (WpT: [s][t])
#define OFF_QF  (OFF_WPT + 1572864ull)        // bf16 flat Q ; reused as KT
#define OFF_KF  (OFF_QF + 33554432ull)        // bf16 flat K ; reused as VT
#define OFF_VF  (OFF_KF + 33554432ull)        // bf16 flat V
// total = OFF_VF + 33554432 = 142,082,048 bytes

// ---------------- k_cast: fp32 -> bf16, 8 elems/thread ----------------
extern "C" __global__ __launch_bounds__(256) void k_cast(
    const float* __restrict__ src, ushort_t* __restrict__ dst) {
  int i = blockIdx.x * 256 + threadIdx.x;          // 0..2097151 (x8 = 16.7M)
  const float4* s = (const float4*)src + (size_t)i * 2;
  float4 a = s[0], b = s[1];
  ushort8 o;
  o[0] = f2b(a.x); o[1] = f2b(a.y); o[2] = f2b(a.z); o[3] = f2b(a.w);
  o[4] = f2b(b.x); o[5] = f2b(b.y); o[6] = f2b(b.z); o[7] = f2b(b.w);
  *((ushort8*)dst + i) = o;
}

// ---------------- k_wt: transpose+cast weights ----------------
extern "C" __global__ __launch_bounds__(256) void k_wt(
    const float* __restrict__ s0, const float* __restrict__ s1,
    const float* __restrict__ s2, const float* __restrict__ s3,
    ushort_t* __restrict__ d0, ushort_t* __restrict__ d1,
    ushort_t* __restrict__ d2, ushort_t* __restrict__ d3) {
  int z = blockIdx.z;
  const float* src = (z == 0) ? s0 : (z == 1) ? s1 : (z == 2) ? s2 : s3;
  ushort_t* dst    = (z == 0) ? d0 : (z == 1) ? d1 : (z == 2) ? d2 : d3;
  int R = (z == 3) ? 1536 : 1024;
  int C = (z == 3) ? 512  : 1024;
  int c0 = blockIdx.x * 64, r0 = blockIdx.y * 64;
  if (c0 >= C || r0 >= R) return;
  __shared__ ushort_t tl[64][80];
  int t = threadIdx.x;
  {
    int lr = t >> 2, cg = (t & 3) * 16;
    const float* sp = src + (size_t)(r0 + lr) * C + c0 + cg;
    #pragma unroll
    for (int i = 0; i < 16; ++i) tl[lr][cg + i] = f2b(sp[i]);
  }
  __syncthreads();
  {
    int lc = t >> 2, rg = (t & 3) * 16;
    ushort_t* dp = dst + (size_t)(c0 + lc) * R + r0 + rg;
    #pragma unroll
    for (int i = 0; i < 16; ++i) dp[i] = tl[rg + i][lc];
  }
}

// ---------------- k_qkv: C = hsb @ W^T(t) + bias, bf16 out ----------------
// A: hsb [16384][1024] bf16 row-major. B: WT [n][k] bf16 (K-contiguous rows).
// 128x128 tile, BK=32, 256 thr = 4 waves (2x2), each wave 64x64 = 4x4 frags of 16x16x32.
extern "C" __global__ __launch_bounds__(256) void k_qkv(
    const ushort_t* __restrict__ A,
    const ushort_t* __restrict__ WTq, const ushort_t* __restrict__ WTk, const ushort_t* __restrict__ WTv,
    const float* __restrict__ bq, const float* __restrict__ bk, const float* __restrict__ bv,
    ushort_t* __restrict__ Qf, ushort_t* __restrict__ Kf, ushort_t* __restrict__ Vf) {
  int z = blockIdx.z;
  const ushort_t* WT = (z == 0) ? WTq : (z == 1) ? WTk : WTv;
  const float* bias  = (z == 0) ? bq  : (z == 1) ? bk  : bv;
  ushort_t* out      = (z == 0) ? Qf  : (z == 1) ? Kf  : Vf;
  int n0 = blockIdx.x * 128, m0 = blockIdx.y * 128;

  __shared__ ushort_t lA[128 * 32];
  __shared__ ushort_t lB[128 * 32];
  int t = threadIdx.x, lane = t & 63, wave = t >> 6;
  int wr = (wave >> 1) * 64, wc = (wave & 1) * 64;

  f32x4 acc[4][4];
  #pragma unroll
  for (int mi = 0; mi < 4; ++mi)
    #pragma unroll
    for (int ni = 0; ni < 4; ++ni)
      acc[mi][ni] = (f32x4){0.f, 0.f, 0.f, 0.f};

  for (int k0 = 0; k0 < 1024; k0 += 32) {
    #pragma unroll
    for (int j = 0; j < 2; ++j) {        // A tile: 128x32 = 512 x 16B units
      int u = j * 256 + t;
      ASYNC16(A + (size_t)(m0 + (u >> 2)) * 1024 + k0 + (u & 3) * 8,
              (char*)lA + (j * 256 + wave * 64) * 16);
    }
    #pragma unroll
    for (int j = 0; j < 2; ++j) {        // B tile: 128 n-rows x 32 k
      int u = j * 256 + t;
      ASYNC16(WT + (size_t)(n0 + (u >> 2)) * 1024 + k0 + (u & 3) * 8,
              (char*)lB + (j * 256 + wave * 64) * 16);
    }
    __syncthreads();
    short8 af[4], bf[4];
    #pragma unroll
    for (int mi = 0; mi < 4; ++mi)
      af[mi] = *(const short8*)&lA[(wr + mi * 16 + (lane & 15)) * 32 + (lane >> 4) * 8];
    #pragma unroll
    for (int ni = 0; ni < 4; ++ni)
      bf[ni] = *(const short8*)&lB[(wc + ni * 16 + (lane & 15)) * 32 + (lane >> 4) * 8];
    #pragma unroll
    for (int mi = 0; mi < 4; ++mi)
      #pragma unroll
      for (int ni = 0; ni < 4; ++ni)
        acc[mi][ni] = __builtin_amdgcn_mfma_f32_16x16x32_bf16(af[mi], bf[ni], acc[mi][ni], 0, 0, 0);
    __syncthreads();
  }
  // epilogue: C/D layout col = lane&15, row = (lane>>4)*4 + r
  #pragma unroll
  for (int ni = 0; ni < 4; ++ni) {
    int gc = n0 + wc + ni * 16 + (lane & 15);
    float bv_ = bias[gc];
    #pragma unroll
    for (int mi = 0; mi < 4; ++mi) {
      int gr = m0 + wr + mi * 16 + ((lane >> 4) << 2);
      #pragma unroll
      for (int r = 0; r < 4; ++r)
        out[(size_t)(gr + r) * 1024 + gc] = f2b(acc[mi][ni][r] + bv_);
    }
  }
}

// ---------------- k_tr: per-(b,n) 512x64 -> 64x512 transpose (bf16) ----------------
extern "C" __global__ __launch_bounds__(256) void k_tr(
    const ushort_t* __restrict__ src, ushort_t* __restrict__ dst) {
  int bn = blockIdx.x;
  const ushort_t* s = src + (size_t)bn * 32768;
  ushort_t* d = dst + (size_t)bn * 32768;
  __shared__ ushort_t tl[64][80];   // [d][s-chunk], pad to keep 16B alignment
  int t = threadIdx.x;
  for (int c = 0; c < 8; ++c) {
    #pragma unroll
    for (int j = 0; j < 2; ++j) {   // load 64 s-rows x 64 d, scatter-transpose into LDS
      int u = j * 256 + t;
      int row = u >> 3, ch = (u & 7) * 8;
      uint4 v = *(const uint4*)&s[(size_t)(c * 64 + row) * 64 + ch];
      const ushort_t* pv = (const ushort_t*)&v;
      #pragma unroll
      for (int i = 0; i < 8; ++i) tl[ch + i][row] = pv[i];
    }
    __syncthreads();
    #pragma unroll
    for (int j = 0; j < 2; ++j) {   // write 64 d-rows x 64 s contiguous
      int u = j * 256 + t;
      int dd = u >> 3, ch = (u & 7) * 8;
      *(uint4*)&d[(size_t)dd * 512 + c * 64 + ch] = *(const uint4*)&tl[dd][ch];
    }
    __syncthreads();
  }
}

// ---------------- k_gv: fused gv GEMM + blend + output ----------------
// Per (b,n,s-half): C[256 s][64 d] = WpT[s][t] @ qkvT[t][d], K=1536.
// 256 thr = 4 waves stacked on M; wave 64x64 = 4x4 frags; BK=64 (2 MFMA k-chunks).
extern "C" __global__ __launch_bounds__(256) void k_gv(
    const ushort_t* __restrict__ WpT,
    const ushort_t* __restrict__ QT, const ushort_t* __restrict__ KT, const ushort_t* __restrict__ VT,
    const float* __restrict__ bp, float* __restrict__ out) {
  int sh = blockIdx.x;            // s-half 0/1
  int bn = blockIdx.y;            // 0..511
  int b = bn >> 4, nh = bn & 15;
  int s0 = sh * 256;
  int t = threadIdx.x, lane = t & 63, wave = t >> 6;

  __shared__ ushort_t lA[256 * 64];   // WpT tile [256 s][64 t]
  __shared__ ushort_t lB[64 * 64];    // qkvT tile [64 d][64 t]
  __shared__ float p0s[256];

  const ushort_t* QTb = QT + (size_t)bn * 32768;
  const ushort_t* KTb = KT + (size_t)bn * 32768;
  const ushort_t* VTb = VT + (size_t)bn * 32768;

  // phase 0: local score p0 = sigmoid((q.k)/8) per s-row
  {
    int s2 = s0 + t;
    float dot = 0.f;
    #pragma unroll 8
    for (int d = 0; d < 64; ++d)
      dot += b2f(QTb[(size_t)d * 512 + s2]) * b2f(KTb[(size_t)d * 512 + s2]);
    p0s[t] = 1.0f / (1.0f + __expf(-dot * 0.125f));
  }

  f32x4 acc[4][4];
  #pragma unroll
  for (int mi = 0; mi < 4; ++mi)
    #pragma unroll
    for (int ni = 0; ni < 4; ++ni)
      acc[mi][ni] = (f32x4){0.f, 0.f, 0.f, 0.f};

  for (int kt = 0; kt < 24; ++kt) {
    int t0 = kt * 64;
    const ushort_t* XT = (t0 < 512) ? QTb : (t0 < 1024) ? KTb : VTb;
    int t0l = t0 & 511;
    #pragma unroll
    for (int j = 0; j < 8; ++j) {       // A: 256x64 = 2048 units
      int u = j * 256 + t;
      ASYNC16(WpT + (size_t)(s0 + (u >> 3)) * 1536 + t0 + (u & 7) * 8,
              (char*)lA + (j * 256 + wave * 64) * 16);
    }
    #pragma unroll
    for (int j = 0; j < 2; ++j) {       // B: 64x64 = 512 units
      int u = j * 256 + t;
      ASYNC16(XT + (size_t)(u >> 3) * 512 + t0l + (u & 7) * 8,
              (char*)lB + (j * 256 + wave * 64) * 16);
    }
    __syncthreads();
    #pragma unroll
    for (int kk = 0; kk < 2; ++kk) {
      short8 af[4], bf[4];
      #pragma unroll
      for (int mi = 0; mi < 4; ++mi)
        af[mi] = *(const short8*)&lA[(wave * 64 + mi * 16 + (lane & 15)) * 64 + kk * 32 + (lane >> 4) * 8];
      #pragma unroll
      for (int ni = 0; ni < 4; ++ni)
        bf[ni] = *(const short8*)&lB[(ni * 16 + (lane & 15)) * 64 + kk * 32 + (lane >> 4) * 8];
      #pragma unroll
      for (int mi = 0; mi < 4; ++mi)
        #pragma unroll
        for (int ni = 0; ni < 4; ++ni)
          acc[mi][ni] = __builtin_amdgcn_mfma_f32_16x16x32_bf16(af[mi], bf[ni], acc[mi][ni], 0, 0, 0);
    }
    __syncthreads();
  }

  // epilogue: ctx = p0*v + (1-p0)*gelu(gv + bp); out[b][s2][nh*64+d]
  size_t outb = (size_t)b * 512 * 1024 + (size_t)nh * 64;
  #pragma unroll
  for (int mi = 0; mi < 4; ++mi) {
    int sl = wave * 64 + mi * 16 + ((lane >> 4) << 2);
    #pragma unroll
    for (int r = 0; r < 4; ++r) {
      int s2 = s0 + sl + r;
      float p0 = p0s[sl + r];
      float bpv = bp[s2];
      #pragma unroll
      for (int ni = 0; ni < 4; ++ni) {
        int d = ni * 16 + (lane & 15);
        float g = acc[mi][ni][r] + bpv;
        float ge = 0.5f * g * (1.0f + erff(g / 1.41421f));
        float v = b2f(VTb[(size_t)d * 512 + s2]);
        out[outb + (size_t)s2 * 1024 + d] = p0 * v + (1.0f - p0) * ge;
      }
    }
  }
}

extern "C" void kernel_launch(void* const* d_in, const int* in_sizes, int n_in,
                              void* d_out, int out_size, void* d_ws, size_t ws_size,
                              hipStream_t stream) {
  const float* hs = (const float*)d_in[0];
  const float* Wq = (const float*)d_in[1];
  const float* bq = (const float*)d_in[2];
  const float* Wk = (const float*)d_in[3];
  const float* bk = (const float*)d_in[4];
  const float* Wv = (const float*)d_in[5];
  const float* bv = (const float*)d_in[6];
  const float* Wp = (const float*)d_in[7];
  const float* bp = (const float*)d_in[8];

  char* w = (char*)d_ws;
  ushort_t* hsb = (ushort_t*)(w + OFF_HSB);
  ushort_t* WqT = (ushort_t*)(w + OFF_WQT);
  ushort_t* WkT = (ushort_t*)(w + OFF_WKT);
  ushort_t* WvT = (ushort_t*)(w + OFF_WVT);
  ushort_t* WpT = (ushort_t*)(w + OFF_WPT);
  ushort_t* Qf  = (ushort_t*)(w + OFF_QF);
  ushort_t* Kf  = (ushort_t*)(w + OFF_KF);
  ushort_t* Vf  = (ushort_t*)(w + OFF_VF);
  // transposed tensors alias dead buffers (sequential launches keep this safe)
  ushort_t* QTt = (ushort_t*)(w + OFF_HSB);
  ushort_t* KTt = (ushort_t*)(w + OFF_QF);
  ushort_t* VTt = (ushort_t*)(w + OFF_KF);

  k_cast<<<8192, 256, 0, stream>>>(hs, hsb);
  k_wt<<<dim3(16, 24, 4), 256, 0, stream>>>(Wq, Wk, Wv, Wp, WqT, WkT, WvT, WpT);
  k_qkv<<<dim3(8, 128, 3), 256, 0, stream>>>(hsb, WqT, WkT, WvT, bq, bk, bv, Qf, Kf, Vf);
  k_tr<<<512, 256, 0, stream>>>(Qf, QTt);   // QT overwrites hsb (dead after k_qkv)
  k_tr<<<512, 256, 0, stream>>>(Kf, KTt);   // KT overwrites Qf (dead after previous k_tr)
  k_tr<<<512, 256, 0, stream>>>(Vf, VTt);   // VT overwrites Kf
  k_gv<<<dim3(2, 512), 256, 0, stream>>>(WpT, QTt, KTt, VTt, bp, (float*)d_out);
}

// Round 3
// 413.060 us; speedup vs baseline: 1.0460x; 1.0460x over previous
//
#include <hip/hip_runtime.h>

// LongformerSelfAttention (B=32,S=512,H=1024,NH=16,HD=64)
// Round 3 = round-1 (known good) + XCD-aware tile swizzle in k_qkv ONLY.
// Pipeline:
//  k_cast : hidden fp32 -> bf16
//  k_wt   : Wq/Wk/Wv (1024x1024) and Wp (1536x512) -> transposed bf16
//  k_qkv  : Q/K/V = hs @ W + b, MFMA 128x128x32 tiles (XCD-swizzled), flat bf16 out
//  k_tr   : per-(b,n) 512x64 -> 64x512 transpose (d-major QT/KT/VT)
//  k_gv   : per-(b,n) gv GEMM (WpT @ qkv^T) + sigmoid(q.k/8) blend + gelu + output

typedef unsigned short ushort_t;
typedef __attribute__((ext_vector_type(8))) short short8;
typedef __attribute__((ext_vector_type(8))) unsigned short ushort8;
typedef __attribute__((ext_vector_type(4))) float f32x4;

#define ASYNC16(gp, lp) __builtin_amdgcn_global_load_lds( \
    (const __attribute__((address_space(1))) void*)(gp),  \
    (__attribute__((address_space(3))) void*)(lp), 16, 0, 0)

__device__ __forceinline__ ushort_t f2b(float f) {
  union { float f; unsigned int u; } v; v.f = f;
  unsigned int r = v.u + 0x7FFFu + ((v.u >> 16) & 1u);
  return (ushort_t)(r >> 16);
}
__device__ __forceinline__ float b2f(ushort_t b) {
  union { unsigned int u; float f; } v; v.u = ((unsigned int)b) << 16;
  return v.f;
}

// ---- workspace layout (bytes) ----
#define OFF_HSB 0ull                          // bf16[16384*1024] ; reused as QT after k_qkv
#define OFF_WQT (33554432ull)                 // bf16[1024*1024]  (WqT: [n][k])
#define OFF_WKT (OFF_WQT + 2097152ull)
#define OFF_WVT (OFF_WKT + 2097152ull)
#define OFF_WPT (OFF_WVT + 2097152ull)        // bf16[512*1536]   (WpT: [s][t])
#define OFF_QF  (OFF_WPT + 1572864ull)        // bf16 flat Q ; reused as KT
#define OFF_KF  (OFF_QF + 33554432ull)        // bf16 flat K ; reused as VT
#define OFF_VF  (OFF_KF + 33554432ull)        // bf16 flat V
// total = OFF_VF + 33554432 = 142,082,048 bytes

// ---------------- k_cast: fp32 -> bf16, 8 elems/thread ----------------
extern "C" __global__ __launch_bounds__(256) void k_cast(
    const float* __restrict__ src, ushort_t* __restrict__ dst) {
  int i = blockIdx.x * 256 + threadIdx.x;          // 0..2097151 (x8 = 16.7M)
  const float4* s = (const float4*)src + (size_t)i * 2;
  float4 a = s[0], b = s[1];
  ushort8 o;
  o[0] = f2b(a.x); o[1] = f2b(a.y); o[2] = f2b(a.z); o[3] = f2b(a.w);
  o[4] = f2b(b.x); o[5] = f2b(b.y); o[6] = f2b(b.z); o[7] = f2b(b.w);
  *((ushort8*)dst + i) = o;
}

// ---------------- k_wt: transpose+cast weights ----------------
extern "C" __global__ __launch_bounds__(256) void k_wt(
    const float* __restrict__ s0, const float* __restrict__ s1,
    const float* __restrict__ s2, const float* __restrict__ s3,
    ushort_t* __restrict__ d0, ushort_t* __restrict__ d1,
    ushort_t* __restrict__ d2, ushort_t* __restrict__ d3) {
  int z = blockIdx.z;
  const float* src = (z == 0) ? s0 : (z == 1) ? s1 : (z == 2) ? s2 : s3;
  ushort_t* dst    = (z == 0) ? d0 : (z == 1) ? d1 : (z == 2) ? d2 : d3;
  int R = (z == 3) ? 1536 : 1024;
  int C = (z == 3) ? 512  : 1024;
  int c0 = blockIdx.x * 64, r0 = blockIdx.y * 64;
  if (c0 >= C || r0 >= R) return;
  __shared__ ushort_t tl[64][80];
  int t = threadIdx.x;
  {
    int lr = t >> 2, cg = (t & 3) * 16;
    const float* sp = src + (size_t)(r0 + lr) * C + c0 + cg;
    #pragma unroll
    for (int i = 0; i < 16; ++i) tl[lr][cg + i] = f2b(sp[i]);
  }
  __syncthreads();
  {
    int lc = t >> 2, rg = (t & 3) * 16;
    ushort_t* dp = dst + (size_t)(c0 + lc) * R + r0 + rg;
    #pragma unroll
    for (int i = 0; i < 16; ++i) dp[i] = tl[rg + i][lc];
  }
}

// ---------------- k_qkv: C = hsb @ W^T(t) + bias, bf16 out ----------------
// A: hsb [16384][1024] bf16 row-major. B: WT [n][k] bf16 (K-contiguous rows).
// 128x128 tile, BK=32, 256 thr = 4 waves (2x2), each wave 64x64 = 4x4 frags of 16x16x32.
// XCD swizzle: dispatch linear index glin round-robins over 8 XCDs; remap so each
// XCD owns a contiguous band of 16 m-tiles (A panel = 4MB = one XCD L2).
extern "C" __global__ __launch_bounds__(256) void k_qkv(
    const ushort_t* __restrict__ A,
    const ushort_t* __restrict__ WTq, const ushort_t* __restrict__ WTk, const ushort_t* __restrict__ WTv,
    const float* __restrict__ bq, const float* __restrict__ bk, const float* __restrict__ bv,
    ushort_t* __restrict__ Qf, ushort_t* __restrict__ Kf, ushort_t* __restrict__ Vf) {
  int z = blockIdx.z;
  const ushort_t* WT = (z == 0) ? WTq : (z == 1) ? WTk : WTv;
  const float* bias  = (z == 0) ? bq  : (z == 1) ? bk  : bv;
  ushort_t* out      = (z == 0) ? Qf  : (z == 1) ? Kf  : Vf;

  // XCD-aware bijective remap (1024 blocks, 8 XCDs):
  int glin = blockIdx.y * 8 + blockIdx.x;        // dispatch-linear, xcd = glin & 7
  int nl = (glin & 7) * 128 + (glin >> 3);       // xcd gets contiguous nl band
  int n0 = (nl & 7) * 128, m0 = (nl >> 3) * 128;

  __shared__ ushort_t lA[128 * 32];
  __shared__ ushort_t lB[128 * 32];
  int t = threadIdx.x, lane = t & 63, wave = t >> 6;
  int wr = (wave >> 1) * 64, wc = (wave & 1) * 64;

  f32x4 acc[4][4];
  #pragma unroll
  for (int mi = 0; mi < 4; ++mi)
    #pragma unroll
    for (int ni = 0; ni < 4; ++ni)
      acc[mi][ni] = (f32x4){0.f, 0.f, 0.f, 0.f};

  for (int k0 = 0; k0 < 1024; k0 += 32) {
    #pragma unroll
    for (int j = 0; j < 2; ++j) {        // A tile: 128x32 = 512 x 16B units
      int u = j * 256 + t;
      ASYNC16(A + (size_t)(m0 + (u >> 2)) * 1024 + k0 + (u & 3) * 8,
              (char*)lA + (j * 256 + wave * 64) * 16);
    }
    #pragma unroll
    for (int j = 0; j < 2; ++j) {        // B tile: 128 n-rows x 32 k
      int u = j * 256 + t;
      ASYNC16(WT + (size_t)(n0 + (u >> 2)) * 1024 + k0 + (u & 3) * 8,
              (char*)lB + (j * 256 + wave * 64) * 16);
    }
    __syncthreads();
    short8 af[4], bf[4];
    #pragma unroll
    for (int mi = 0; mi < 4; ++mi)
      af[mi] = *(const short8*)&lA[(wr + mi * 16 + (lane & 15)) * 32 + (lane >> 4) * 8];
    #pragma unroll
    for (int ni = 0; ni < 4; ++ni)
      bf[ni] = *(const short8*)&lB[(wc + ni * 16 + (lane & 15)) * 32 + (lane >> 4) * 8];
    #pragma unroll
    for (int mi = 0; mi < 4; ++mi)
      #pragma unroll
      for (int ni = 0; ni < 4; ++ni)
        acc[mi][ni] = __builtin_amdgcn_mfma_f32_16x16x32_bf16(af[mi], bf[ni], acc[mi][ni], 0, 0, 0);
    __syncthreads();
  }
  // epilogue: C/D layout col = lane&15, row = (lane>>4)*4 + r
  #pragma unroll
  for (int ni = 0; ni < 4; ++ni) {
    int gc = n0 + wc + ni * 16 + (lane & 15);
    float bv_ = bias[gc];
    #pragma unroll
    for (int mi = 0; mi < 4; ++mi) {
      int gr = m0 + wr + mi * 16 + ((lane >> 4) << 2);
      #pragma unroll
      for (int r = 0; r < 4; ++r)
        out[(size_t)(gr + r) * 1024 + gc] = f2b(acc[mi][ni][r] + bv_);
    }
  }
}

// ---------------- k_tr: per-(b,n) 512x64 -> 64x512 transpose (bf16) ----------------
extern "C" __global__ __launch_bounds__(256) void k_tr(
    const ushort_t* __restrict__ src, ushort_t* __restrict__ dst) {
  int bn = blockIdx.x;
  const ushort_t* s = src + (size_t)bn * 32768;
  ushort_t* d = dst + (size_t)bn * 32768;
  __shared__ ushort_t tl[64][80];   // [d][s-chunk], pad to keep 16B alignment
  int t = threadIdx.x;
  for (int c = 0; c < 8; ++c) {
    #pragma unroll
    for (int j = 0; j < 2; ++j) {   // load 64 s-rows x 64 d, scatter-transpose into LDS
      int u = j * 256 + t;
      int row = u >> 3, ch = (u & 7) * 8;
      uint4 v = *(const uint4*)&s[(size_t)(c * 64 + row) * 64 + ch];
      const ushort_t* pv = (const ushort_t*)&v;
      #pragma unroll
      for (int i = 0; i < 8; ++i) tl[ch + i][row] = pv[i];
    }
    __syncthreads();
    #pragma unroll
    for (int j = 0; j < 2; ++j) {   // write 64 d-rows x 64 s contiguous
      int u = j * 256 + t;
      int dd = u >> 3, ch = (u & 7) * 8;
      *(uint4*)&d[(size_t)dd * 512 + c * 64 + ch] = *(const uint4*)&tl[dd][ch];
    }
    __syncthreads();
  }
}

// ---------------- k_gv: fused gv GEMM + blend + output ----------------
// Per (b,n,s-half): C[256 s][64 d] = WpT[s][t] @ qkvT[t][d], K=1536.
// 256 thr = 4 waves stacked on M; wave 64x64 = 4x4 frags; BK=64 (2 MFMA k-chunks).
extern "C" __global__ __launch_bounds__(256) void k_gv(
    const ushort_t* __restrict__ WpT,
    const ushort_t* __restrict__ QT, const ushort_t* __restrict__ KT, const ushort_t* __restrict__ VT,
    const float* __restrict__ bp, float* __restrict__ out) {
  int sh = blockIdx.x;            // s-half 0/1
  int bn = blockIdx.y;            // 0..511
  int b = bn >> 4, nh = bn & 15;
  int s0 = sh * 256;
  int t = threadIdx.x, lane = t & 63, wave = t >> 6;

  __shared__ ushort_t lA[256 * 64];   // WpT tile [256 s][64 t]
  __shared__ ushort_t lB[64 * 64];    // qkvT tile [64 d][64 t]
  __shared__ float p0s[256];

  const ushort_t* QTb = QT + (size_t)bn * 32768;
  const ushort_t* KTb = KT + (size_t)bn * 32768;
  const ushort_t* VTb = VT + (size_t)bn * 32768;

  // phase 0: local score p0 = sigmoid((q.k)/8) per s-row
  {
    int s2 = s0 + t;
    float dot = 0.f;
    #pragma unroll 8
    for (int d = 0; d < 64; ++d)
      dot += b2f(QTb[(size_t)d * 512 + s2]) * b2f(KTb[(size_t)d * 512 + s2]);
    p0s[t] = 1.0f / (1.0f + __expf(-dot * 0.125f));
  }

  f32x4 acc[4][4];
  #pragma unroll
  for (int mi = 0; mi < 4; ++mi)
    #pragma unroll
    for (int ni = 0; ni < 4; ++ni)
      acc[mi][ni] = (f32x4){0.f, 0.f, 0.f, 0.f};

  for (int kt = 0; kt < 24; ++kt) {
    int t0 = kt * 64;
    const ushort_t* XT = (t0 < 512) ? QTb : (t0 < 1024) ? KTb : VTb;
    int t0l = t0 & 511;
    #pragma unroll
    for (int j = 0; j < 8; ++j) {       // A: 256x64 = 2048 units
      int u = j * 256 + t;
      ASYNC16(WpT + (size_t)(s0 + (u >> 3)) * 1536 + t0 + (u & 7) * 8,
              (char*)lA + (j * 256 + wave * 64) * 16);
    }
    #pragma unroll
    for (int j = 0; j < 2; ++j) {       // B: 64x64 = 512 units
      int u = j * 256 + t;
      ASYNC16(XT + (size_t)(u >> 3) * 512 + t0l + (u & 7) * 8,
              (char*)lB + (j * 256 + wave * 64) * 16);
    }
    __syncthreads();
    #pragma unroll
    for (int kk = 0; kk < 2; ++kk) {
      short8 af[4], bf[4];
      #pragma unroll
      for (int mi = 0; mi < 4; ++mi)
        af[mi] = *(const short8*)&lA[(wave * 64 + mi * 16 + (lane & 15)) * 64 + kk * 32 + (lane >> 4) * 8];
      #pragma unroll
      for (int ni = 0; ni < 4; ++ni)
        bf[ni] = *(const short8*)&lB[(ni * 16 + (lane & 15)) * 64 + kk * 32 + (lane >> 4) * 8];
      #pragma unroll
      for (int mi = 0; mi < 4; ++mi)
        #pragma unroll
        for (int ni = 0; ni < 4; ++ni)
          acc[mi][ni] = __builtin_amdgcn_mfma_f32_16x16x32_bf16(af[mi], bf[ni], acc[mi][ni], 0, 0, 0);
    }
    __syncthreads();
  }

  // epilogue: ctx = p0*v + (1-p0)*gelu(gv + bp); out[b][s2][nh*64+d]
  size_t outb = (size_t)b * 512 * 1024 + (size_t)nh * 64;
  #pragma unroll
  for (int mi = 0; mi < 4; ++mi) {
    int sl = wave * 64 + mi * 16 + ((lane >> 4) << 2);
    #pragma unroll
    for (int r = 0; r < 4; ++r) {
      int s2 = s0 + sl + r;
      float p0 = p0s[sl + r];
      float bpv = bp[s2];
      #pragma unroll
      for (int ni = 0; ni < 4; ++ni) {
        int d = ni * 16 + (lane & 15);
        float g = acc[mi][ni][r] + bpv;
        float ge = 0.5f * g * (1.0f + erff(g / 1.41421f));
        float v = b2f(VTb[(size_t)d * 512 + s2]);
        out[outb + (size_t)s2 * 1024 + d] = p0 * v + (1.0f - p0) * ge;
      }
    }
  }
}

extern "C" void kernel_launch(void* const* d_in, const int* in_sizes, int n_in,
                              void* d_out, int out_size, void* d_ws, size_t ws_size,
                              hipStream_t stream) {
  const float* hs = (const float*)d_in[0];
  const float* Wq = (const float*)d_in[1];
  const float* bq = (const float*)d_in[2];
  const float* Wk = (const float*)d_in[3];
  const float* bk = (const float*)d_in[4];
  const float* Wv = (const float*)d_in[5];
  const float* bv = (const float*)d_in[6];
  const float* Wp = (const float*)d_in[7];
  const float* bp = (const float*)d_in[8];

  char* w = (char*)d_ws;
  ushort_t* hsb = (ushort_t*)(w + OFF_HSB);
  ushort_t* WqT = (ushort_t*)(w + OFF_WQT);
  ushort_t* WkT = (ushort_t*)(w + OFF_WKT);
  ushort_t* WvT = (ushort_t*)(w + OFF_WVT);
  ushort_t* WpT = (ushort_t*)(w + OFF_WPT);
  ushort_t* Qf  = (ushort_t*)(w + OFF_QF);
  ushort_t* Kf  = (ushort_t*)(w + OFF_KF);
  ushort_t* Vf  = (ushort_t*)(w + OFF_VF);
  // transposed tensors alias dead buffers (sequential launches keep this safe)
  ushort_t* QTt = (ushort_t*)(w + OFF_HSB);
  ushort_t* KTt = (ushort_t*)(w + OFF_QF);
  ushort_t* VTt = (ushort_t*)(w + OFF_KF);

  k_cast<<<8192, 256, 0, stream>>>(hs, hsb);
  k_wt<<<dim3(16, 24, 4), 256, 0, stream>>>(Wq, Wk, Wv, Wp, WqT, WkT, WvT, WpT);
  k_qkv<<<dim3(8, 128, 3), 256, 0, stream>>>(hsb, WqT, WkT, WvT, bq, bk, bv, Qf, Kf, Vf);
  k_tr<<<512, 256, 0, stream>>>(Qf, QTt);   // QT overwrites hsb (dead after k_qkv)
  k_tr<<<512, 256, 0, stream>>>(Kf, KTt);   // KT overwrites Qf (dead after previous k_tr)
  k_tr<<<512, 256, 0, stream>>>(Vf, VTt);   // VT overwrites Kf
  k_gv<<<dim3(2, 512), 256, 0, stream>>>(WpT, QTt, KTt, VTt, bp, (float*)d_out);
}